// Round 12
// baseline (54.195 us; speedup 1.0000x reference)
//
#include <hip/hip_runtime.h>

#define HH 128
#define WW 256
#define NCP 32           // 64 channels -> 32 channel-pairs
#define PLANE 32768      // H*W dwords per fp32 channel plane
#define AHEAD 2          // channel-pairs in flight (4 loads each)

typedef unsigned int u32;
typedef _Float16 f16;
typedef f16 f16x2 __attribute__((ext_vector_type(2)));
typedef u32 u32x4 __attribute__((ext_vector_type(4)));

union U32H2 { u32 u; f16x2 h; };

// Fused pack+correlate. wave = (b,h,dy), fully independent, no barriers.
// Per channel-pair: 4x global dwordx4 (fp32 rows S_c,S_c+1,F_c,F_c+1) -> regs,
// RNE-convert+pack to f16x2, ds_write one 264-dword padded row, then 3x
// ds_read_b128 window + 36 dot2. The ds_write->ds_read pair is CROSS-LANE
// (lane i reads lanes i-1,i+1's dwords): hardware DS is in-order per wave,
// but the compiler's per-lane alias model thinks s0/s2 don't alias the
// write -> must pin with an explicit compiler memory barrier (R11 bug).
__global__ __launch_bounds__(256, 4) void corr_fused(
    const float* __restrict__ first,
    const float* __restrict__ second,
    float* __restrict__ out)
{
  __shared__ u32 lds[4][264];               // one padded row per wave, 4224 B

  const int tid  = threadIdx.x;
  const int lane = tid & 63;
  const int wv   = __builtin_amdgcn_readfirstlane(tid >> 6);  // 0..3
  const int bid  = blockIdx.x;
  const int xcd  = bid & 7;                 // contiguous 16-row h band per XCD
  const int idx  = bid >> 3;                // 0..143
  const int rest = idx * 4 + wv;            // 0..575 within this XCD
  const int h    = xcd * 16 + (rest & 15);
  const int r2   = rest >> 4;               // 0..35
  const int b    = r2 & 3;
  const int dy   = r2 >> 2;                 // 0..8
  const int l4   = lane * 4;

  float* obase = out + (((size_t)(b * 81 + dy * 9)) * HH + h) * WW + l4;
  const int gh = h + dy - 4;
  if (gh < 0 || gh >= HH) {                 // whole row OOB -> zeros, exit
    const float4 z = make_float4(0.f, 0.f, 0.f, 0.f);
#pragma unroll
    for (int dx = 0; dx < 9; ++dx) *(float4*)(obase + (size_t)dx * PLANE) = z;
    return;
  }

  u32* S = &lds[wv][0];                     // [4 pad | 256 | 4 pad] dwords
  if (lane < 8)                             // zero side pads once (wave-private;
    S[lane < 4 ? lane : 256 + lane] = 0;    // per-iter writes only touch 4..259)

  const float* srow = second + ((size_t)(b * 64) * HH + gh) * WW + l4;
  const float* frow = first  + ((size_t)(b * 64) * HH + h ) * WW + l4;

  // Register landing zones; all indices compile-time under full unroll.
  float4 sx[2], sy[2], fx[2], fy[2];

#define PAIR(cp) do {                                             \
    const size_t o = (size_t)(2 * (cp)) * PLANE;                  \
    sx[(cp) & 1] = *(const float4*)(srow + o);                    \
    sy[(cp) & 1] = *(const float4*)(srow + o + PLANE);            \
    fx[(cp) & 1] = *(const float4*)(frow + o);                    \
    fy[(cp) & 1] = *(const float4*)(frow + o + PLANE);            \
  } while (0)

  PAIR(0); PAIR(1);                         // 8 loads in flight

  float acc[36];
#pragma unroll
  for (int k = 0; k < 36; ++k) acc[k] = 0.f;

#pragma unroll
  for (int cp = 0; cp < NCP; ++cp) {
    // Drain pair cp (its 4 loads); keep pair cp+1 (4 loads) in flight.
    if (cp < NCP - 1) asm volatile("s_waitcnt vmcnt(4)" ::: "memory");
    else              asm volatile("s_waitcnt vmcnt(0)" ::: "memory");
    __builtin_amdgcn_sched_barrier(0);      // nothing below hoists above the wait
    const int par = cp & 1;

    // RNE fp32->f16, pack (c in lo, c+1 in hi).
    U32H2 sd0, sd1, sd2, sd3, fd0, fd1, fd2, fd3;
    sd0.h = f16x2{(f16)sx[par].x, (f16)sy[par].x};
    sd1.h = f16x2{(f16)sx[par].y, (f16)sy[par].y};
    sd2.h = f16x2{(f16)sx[par].z, (f16)sy[par].z};
    sd3.h = f16x2{(f16)sx[par].w, (f16)sy[par].w};
    *(u32x4*)(S + 4 + l4) = (u32x4){sd0.u, sd1.u, sd2.u, sd3.u};  // ds_write_b128
    fd0.h = f16x2{(f16)fx[par].x, (f16)fy[par].x};
    fd1.h = f16x2{(f16)fx[par].y, (f16)fy[par].y};
    fd2.h = f16x2{(f16)fx[par].z, (f16)fy[par].z};
    fd3.h = f16x2{(f16)fx[par].w, (f16)fy[par].w};

    if (cp + AHEAD < NCP) PAIR(cp + AHEAD); // landing regs freed by cvt above

    // --- cross-lane RAW fence: reads below must not move above the ds_write.
    asm volatile("" ::: "memory");          // IR-level: no hoist/forward across
    __builtin_amdgcn_sched_barrier(0);      // MIR-level: scheduler pinned

    // Window: dwords l4-4 .. l4+7 of the padded row (pads give zero edges).
    const u32x4 s0 = *(const u32x4*)(S + l4);
    const u32x4 s1 = *(const u32x4*)(S + l4 + 4);
    const u32x4 s2 = *(const u32x4*)(S + l4 + 8);

    U32H2 f_[4], s_[12];
    f_[0] = fd0; f_[1] = fd1; f_[2] = fd2; f_[3] = fd3;
#pragma unroll
    for (int j = 0; j < 4; ++j) { s_[j].u = s0[j]; s_[j + 4].u = s1[j]; s_[j + 8].u = s2[j]; }
#pragma unroll
    for (int dx = 0; dx < 9; ++dx)
#pragma unroll
      for (int i = 0; i < 4; ++i)
        acc[dx * 4 + i] = __builtin_amdgcn_fdot2(f_[i].h, s_[i + dx].h,
                                                 acc[dx * 4 + i], false);
  }
#undef PAIR

  const float sc = 1.0f / 64.0f;
#pragma unroll
  for (int dx = 0; dx < 9; ++dx) {
    float4 v = make_float4(acc[dx * 4 + 0] * sc, acc[dx * 4 + 1] * sc,
                           acc[dx * 4 + 2] * sc, acc[dx * 4 + 3] * sc);
    *(float4*)(obase + (size_t)dx * PLANE) = v;
  }
}

extern "C" void kernel_launch(void* const* d_in, const int* in_sizes, int n_in,
                              void* d_out, int out_size, void* d_ws, size_t ws_size,
                              hipStream_t stream) {
  const float* first  = (const float*)d_in[0];
  const float* second = (const float*)d_in[1];
  float* out = (float*)d_out;
  (void)in_sizes; (void)n_in; (void)out_size; (void)d_ws; (void)ws_size;
  corr_fused<<<dim3(1152), dim3(256), 0, stream>>>(first, second, out);
}

// Round 13
// 38.577 us; speedup vs baseline: 1.4049x; 1.4049x over previous
//
#include <hip/hip_runtime.h>

#define HH 128
#define WW 256
#define DEPTH 4          // LDS/F ring slots per wave
#define AHEAD 3          // channel-pairs in flight; 3 vmem per pair
#define NCP 32           // 64 channels -> 32 channel-pairs
#define PLANE 32768      // H*W dwords per plane
#define PACKED_DWORDS 4194304ull   // 4 b * 32 cp * 32768 (packed S)

typedef unsigned int u32;
typedef _Float16 f16;
typedef f16 f16x2 __attribute__((ext_vector_type(2)));
typedef u32 u32x4 __attribute__((ext_vector_type(4)));

union U32H2 { u32 u; f16x2 h; };

// async global->LDS, 16B/lane: global src per-lane, LDS dest uniform base + lane*16.
__device__ __forceinline__ void gload_lds16(const u32* g, u32* l) {
  __builtin_amdgcn_global_load_lds(
      (const __attribute__((address_space(1))) u32*)g,
      (__attribute__((address_space(3))) u32*)l, 16, 0, 0);
}

__device__ __forceinline__ void waitv(int n) {   // n compile-time after unroll
  if      (n >= 6) asm volatile("s_waitcnt vmcnt(6)" ::: "memory");
  else if (n == 3) asm volatile("s_waitcnt vmcnt(3)" ::: "memory");
  else             asm volatile("s_waitcnt vmcnt(0)" ::: "memory");
}

// ---- pack S only: fp32 [b][c][h][w] -> dword=half2(c,c+1) at [b][c/2][h][w] ----
__global__ __launch_bounds__(256) void pack_s(
    const float* __restrict__ src, u32* __restrict__ dst)
{
  const int di  = blockIdx.x * 1024 + threadIdx.x * 4;  // packed dword idx, 16B-aligned
  const int p   = di & (PLANE - 1);
  const int cpb = di >> 15;                 // b*32 + cp
  const int bI  = cpb >> 5, cp = cpb & 31;
  const size_t s0 = ((size_t)(bI * 64 + cp * 2)) * PLANE + p;
  const float4 x = *(const float4*)(src + s0);
  const float4 y = *(const float4*)(src + s0 + PLANE);
  U32H2 h0, h1, h2, h3;
  h0.h = f16x2{(f16)x.x, (f16)y.x};
  h1.h = f16x2{(f16)x.y, (f16)y.y};
  h2.h = f16x2{(f16)x.z, (f16)y.z};
  h3.h = f16x2{(f16)x.w, (f16)y.w};
  *(u32x4*)(dst + di) = (u32x4){h0.u, h1.u, h2.u, h3.u};
}

// ---- correlation: block=(b,h), 9 dy-waves. S from packed ws via LDS ring;
// F read fp32 directly (9 colocated waves L1-merge the identical address),
// converted to f16x2 in-register. No barriers. ----
__global__ __launch_bounds__(576, 5) void corr_f16(
    const u32* __restrict__ ps, const float* __restrict__ first,
    float* __restrict__ out)
{
  __shared__ u32 lds[9][DEPTH * 264];              // 38016 B/block

  const int tid  = threadIdx.x;
  const int lane = tid & 63;
  const int dy   = __builtin_amdgcn_readfirstlane(tid >> 6);  // 0..8, wave-uniform
  const int bid  = blockIdx.x;
  const int xcd  = bid & 7;                 // contiguous 16-row h band per XCD
  const int idx  = bid >> 3;                // 0..63
  const int h    = xcd * 16 + (idx & 15);
  const int b    = idx >> 4;                // 0..3
  const int l4   = lane * 4;

  float* obase = out + (((size_t)(b * 81 + dy * 9)) * HH + h) * WW + l4;
  const int gh = h + dy - 4;
  if (gh < 0 || gh >= HH) {                 // whole row OOB -> zeros, exit
    const float4 z = make_float4(0.f, 0.f, 0.f, 0.f);
#pragma unroll
    for (int dx = 0; dx < 9; ++dx) *(float4*)(obase + (size_t)dx * PLANE) = z;
    return;
  }

  u32* S = &lds[dy][0];                     // 4 slots x [4 pad | 256 | 4 pad]
  if (lane < DEPTH * 8) {                   // zero side-pads once (wave-private)
    const int slot = lane >> 3, pd = lane & 7;
    S[slot * 264 + (pd < 4 ? pd : 256 + pd)] = 0;
  }

  const u32*   sg = ps    + (size_t)(b * NCP) * PLANE + (size_t)gh * WW + l4;
  const float* fg = first + (size_t)(b * 64) * PLANE + (size_t)h * WW + l4;

  float4 frx[DEPTH], fry[DEPTH];            // F ring (fp32), compile-time indices

  auto pair = [&](int cp) {                 // 3 vmem: S-gload, F rows c and c+1
    const int slot = cp % DEPTH;
    gload_lds16(sg + (size_t)cp * PLANE, S + slot * 264 + 4);
    frx[slot] = *(const float4*)(fg + (size_t)(2 * cp) * PLANE);
    fry[slot] = *(const float4*)(fg + (size_t)(2 * cp + 1) * PLANE);
  };

#pragma unroll
  for (int cp = 0; cp < AHEAD; ++cp) pair(cp);    // 3 pairs = 9 vmem in flight

  float acc[36];
#pragma unroll
  for (int k = 0; k < 36; ++k) acc[k] = 0.f;

#pragma unroll
  for (int cp = 0; cp < NCP; ++cp) {
    const int rem = NCP - 1 - cp;
    // Drain pair cp (3 ops); leave at most AHEAD-1 pairs (=6 ops) in flight.
    waitv(3 * (rem < AHEAD - 1 ? rem : AHEAD - 1));
    __builtin_amdgcn_sched_barrier(0);      // rule 18: no ds_read above the wait
    const int slot = cp % DEPTH;
    const u32x4 s0 = *(const u32x4*)(S + slot * 264 + l4);       // w-4..w-1
    const u32x4 s1 = *(const u32x4*)(S + slot * 264 + l4 + 4);   // w..w+3
    const u32x4 s2 = *(const u32x4*)(S + slot * 264 + l4 + 8);   // w+4..w+7
    // RNE fp32->f16 pack of F (identical rounding to the old pack kernel).
    U32H2 f_[4];
    f_[0].h = f16x2{(f16)frx[slot].x, (f16)fry[slot].x};
    f_[1].h = f16x2{(f16)frx[slot].y, (f16)fry[slot].y};
    f_[2].h = f16x2{(f16)frx[slot].z, (f16)fry[slot].z};
    f_[3].h = f16x2{(f16)frx[slot].w, (f16)fry[slot].w};
    if (cp + AHEAD < NCP) pair(cp + AHEAD); // landing regs freed by cvt above

    U32H2 s_[12];
#pragma unroll
    for (int j = 0; j < 4; ++j) { s_[j].u = s0[j]; s_[j + 4].u = s1[j]; s_[j + 8].u = s2[j]; }
#pragma unroll
    for (int dx = 0; dx < 9; ++dx)
#pragma unroll
      for (int i = 0; i < 4; ++i)
        acc[dx * 4 + i] = __builtin_amdgcn_fdot2(f_[i].h, s_[i + dx].h,
                                                 acc[dx * 4 + i], false);
  }

  const float sc = 1.0f / 64.0f;
#pragma unroll
  for (int dx = 0; dx < 9; ++dx) {
    float4 v = make_float4(acc[dx * 4 + 0] * sc, acc[dx * 4 + 1] * sc,
                           acc[dx * 4 + 2] * sc, acc[dx * 4 + 3] * sc);
    *(float4*)(obase + (size_t)dx * PLANE) = v;
  }
}

// ---- fallback (proven-correct fp32 path) if ws is too small ----
__global__ __launch_bounds__(576) void corr_fp32_fb(
    const float* __restrict__ first, const float* __restrict__ second,
    float* __restrict__ out)
{
  const int tid  = threadIdx.x;
  const int lane = tid & 63;
  const int wv   = tid >> 6;
  const int bid  = blockIdx.x;
  const int idx  = bid >> 3;
  const int h    = (bid & 7) * 16 + (idx & 15);
  const int b    = idx >> 4;
  const int l4   = lane * 4;
  const size_t plane = (size_t)HH * WW;
  float* obase = out + (((size_t)b * 81 + (size_t)wv * 9) * HH + h) * WW + l4;
  const int gh = h + wv - 4;
  if (gh < 0 || gh >= HH) {
    const float4 z = make_float4(0.f, 0.f, 0.f, 0.f);
#pragma unroll
    for (int dx = 0; dx < 9; ++dx) *(float4*)(obase + (size_t)dx * plane) = z;
    return;
  }
  const float* frow = first  + ((size_t)b * 64 * HH + h ) * WW;
  const float* srow = second + ((size_t)b * 64 * HH + gh) * WW;
  const bool zL = (lane == 0), zR = (lane == 63);
  const int offL = zL ? l4 : l4 - 4;
  const int offR = zR ? l4 : l4 + 4;
  float acc[9][4];
#pragma unroll
  for (int dx = 0; dx < 9; ++dx)
#pragma unroll
    for (int i = 0; i < 4; ++i) acc[dx][i] = 0.f;
#pragma unroll 2
  for (int c = 0; c < 64; ++c) {
    const size_t cp = (size_t)c * plane;
    float4 f  = *(const float4*)(frow + cp + l4);
    float4 aL = *(const float4*)(srow + cp + offL);
    float4 aM = *(const float4*)(srow + cp + l4);
    float4 aR = *(const float4*)(srow + cp + offR);
    if (zL) { aL.x = aL.y = aL.z = aL.w = 0.f; }
    if (zR) { aR.x = aR.y = aR.z = aR.w = 0.f; }
    const float fv[4]  = {f.x, f.y, f.z, f.w};
    const float sv[12] = {aL.x, aL.y, aL.z, aL.w, aM.x, aM.y, aM.z, aM.w,
                          aR.x, aR.y, aR.z, aR.w};
#pragma unroll
    for (int dx = 0; dx < 9; ++dx)
#pragma unroll
      for (int i = 0; i < 4; ++i)
        acc[dx][i] = fmaf(fv[i], sv[i + dx], acc[dx][i]);
  }
  const float sc = 1.0f / 64.0f;
#pragma unroll
  for (int dx = 0; dx < 9; ++dx) {
    float4 v = make_float4(acc[dx][0] * sc, acc[dx][1] * sc,
                           acc[dx][2] * sc, acc[dx][3] * sc);
    *(float4*)(obase + (size_t)dx * plane) = v;
  }
}

extern "C" void kernel_launch(void* const* d_in, const int* in_sizes, int n_in,
                              void* d_out, int out_size, void* d_ws, size_t ws_size,
                              hipStream_t stream) {
  const float* first  = (const float*)d_in[0];
  const float* second = (const float*)d_in[1];
  float* out = (float*)d_out;
  (void)in_sizes; (void)n_in; (void)out_size;

  if (ws_size >= PACKED_DWORDS * 4ull) {
    u32* psecond = (u32*)d_ws;
    pack_s  <<<dim3(4096), dim3(256), 0, stream>>>(second, psecond);
    corr_f16<<<dim3(512),  dim3(576), 0, stream>>>(psecond, first, out);
  } else {
    corr_fp32_fb<<<dim3(512), dim3(576), 0, stream>>>(first, second, out);
  }
}